// Round 1
// baseline (836.789 us; speedup 1.0000x reference)
//
#include <hip/hip_runtime.h>
#include <hip/hip_bf16.h>

#define DIM 256
#define WIN 64
#define HEADS 8
#define HD 32
#define NW 64

typedef __attribute__((ext_vector_type(8))) short bf16x8;
typedef __attribute__((ext_vector_type(4))) float f32x4;

// LDS layout (elements of unsigned short / bf16)
#define XS 264                  // x / attn-out row stride (256 + 8 pad)
#define QS 40                   // q,k row stride (80 B: 16B aligned, 2-way banks)
#define VS 72                   // v-transposed row stride (144 B)
#define PS 72                   // P row stride
#define HREG 7424               // per-head region: q(64*40) + k(64*40) + vt(32*72)
#define LDS_ELEMS (WIN * XS + HEADS * HREG)   // 16896 + 59392 = 76288 (152576 B)

__device__ __forceinline__ unsigned short f2bf(float f) {
  union { float f; unsigned u; } v; v.f = f;
  unsigned r = v.u + 0x7FFFu + ((v.u >> 16) & 1u);   // RNE
  return (unsigned short)(r >> 16);
}

__device__ __forceinline__ bf16x8 ldf(const unsigned short* p) {
  return *reinterpret_cast<const bf16x8*>(p);
}

#define MFMA16(a, b, c) __builtin_amdgcn_mfma_f32_16x16x32_bf16(a, b, c, 0, 0, 0)

// ---------------------------------------------------------------------------
// Prep: transpose+convert weights to bf16 (fold softmax scale into q cols),
// scale q bias, pre-gather relative-position bias rb[h][n][m].
// ---------------------------------------------------------------------------
__global__ void prep_kernel(const float* __restrict__ w_qkv,
                            const float* __restrict__ b_qkv,
                            const float* __restrict__ w_proj,
                            const float* __restrict__ bias_table,
                            unsigned short* __restrict__ wqkv_t,   // [768][256]
                            unsigned short* __restrict__ wproj_t,  // [256][256]
                            float* __restrict__ bqkv_s,            // [768]
                            float* __restrict__ rb) {              // [8][64][64]
  const float SCALE = 0.1767766952966369f;  // 32^-0.5
  int idx = blockIdx.x * blockDim.x + threadIdx.x;
  if (idx < 768 * 256) {
    int n = idx >> 8, k = idx & 255;
    float v = w_qkv[k * 768 + n];
    if (n < 256) v *= SCALE;               // q columns get the scale
    wqkv_t[idx] = f2bf(v);
  }
  if (idx < 256 * 256) {
    int n = idx >> 8, k = idx & 255;
    wproj_t[idx] = f2bf(w_proj[k * 256 + n]);
  }
  if (idx < 768) {
    float v = b_qkv[idx];
    if (idx < 256) v *= SCALE;
    bqkv_s[idx] = v;
  }
  if (idx < HEADS * WIN * WIN) {
    int h = idx >> 12;                     // / 4096
    int r = idx & 4095;
    int n = r >> 6, m = r & 63;
    rb[idx] = bias_table[(n - m + WIN - 1) * HEADS + h];
  }
}

// ---------------------------------------------------------------------------
// Fused window attention: one block per window, wave h owns head h.
// ---------------------------------------------------------------------------
__global__ __launch_bounds__(512, 2) void fused_attn(
    const float* __restrict__ x,          // [4096][64][256]
    const float* __restrict__ mask,       // [64][64][64]
    const float* __restrict__ b_proj,     // [256]
    const unsigned short* __restrict__ wqkv_t,   // [768][256] bf16
    const unsigned short* __restrict__ wproj_t,  // [256][256] bf16
    const float* __restrict__ bqkv_s,     // [768]
    const float* __restrict__ rb,         // [8][64][64]
    float* __restrict__ out) {            // [4096][64][256]
  extern __shared__ unsigned short lds[];
  unsigned short* xs = lds;                                   // [64][XS], later attn-out
  const int tid = threadIdx.x;
  const int wave = tid >> 6;          // head index
  const int lane = tid & 63;
  const int l16 = lane & 15;
  const int quad = lane >> 4;
  const int b = blockIdx.x;
  const int h = wave;

  unsigned short* qh = lds + WIN * XS + h * HREG;             // [64][QS]
  unsigned short* kh = qh + 64 * QS;                          // [64][QS]
  unsigned short* vth = qh + 2 * 64 * QS;                     // [32][VS]
  unsigned short* ph = qh;                                    // [64][PS] overlays q,k

  // ---- Phase 1: load x window -> LDS bf16 ----
  const float4* xg = reinterpret_cast<const float4*>(x + (size_t)b * (WIN * DIM));
#pragma unroll
  for (int i = 0; i < 8; ++i) {
    int e = tid + i * 512;             // float4 index, 4096 total
    float4 f = xg[e];
    int n = e >> 6;
    int c = (e & 63) << 2;
    unsigned short* d = xs + n * XS + c;
    d[0] = f2bf(f.x); d[1] = f2bf(f.y); d[2] = f2bf(f.z); d[3] = f2bf(f.w);
  }
  __syncthreads();

  // ---- Phase 2: qkv GEMM, wave computes 64 x 96 (q|k|v for head h), K=256 ----
  {
    f32x4 acc[6][4];
#pragma unroll
    for (int ct = 0; ct < 6; ++ct)
#pragma unroll
      for (int rt = 0; rt < 4; ++rt) acc[ct][rt] = (f32x4){0.f, 0.f, 0.f, 0.f};

#pragma unroll
    for (int kk = 0; kk < 8; ++kk) {
      int k0 = kk * 32 + quad * 8;
      bf16x8 a[4], bb[6];
#pragma unroll
      for (int rt = 0; rt < 4; ++rt) a[rt] = ldf(xs + (rt * 16 + l16) * XS + k0);
#pragma unroll
      for (int ct = 0; ct < 6; ++ct) {
        int cbase = h * 32 + (ct >> 1) * 256 + (ct & 1) * 16;   // q|k|v column
        bb[ct] = ldf(wqkv_t + (cbase + l16) * 256 + k0);
      }
#pragma unroll
      for (int ct = 0; ct < 6; ++ct)
#pragma unroll
        for (int rt = 0; rt < 4; ++rt) acc[ct][rt] = MFMA16(a[rt], bb[ct], acc[ct][rt]);
    }

    // store q,k row-major [64][QS]; v transposed [32][VS]
#pragma unroll
    for (int ct = 0; ct < 6; ++ct) {
      int cbase = h * 32 + (ct >> 1) * 256 + (ct & 1) * 16;
      float bias = bqkv_s[cbase + l16];
#pragma unroll
      for (int rt = 0; rt < 4; ++rt)
#pragma unroll
        for (int r = 0; r < 4; ++r) {
          int row = rt * 16 + quad * 4 + r;
          unsigned short bv = f2bf(acc[ct][rt][r] + bias);
          if (ct < 2)      qh[row * QS + ct * 16 + l16] = bv;
          else if (ct < 4) kh[row * QS + (ct - 2) * 16 + l16] = bv;
          else             vth[((ct - 4) * 16 + l16) * VS + row] = bv;
        }
    }
  }
  __syncthreads();   // all waves done reading xs; xs becomes attn-out buffer

  // ---- Phase 3: S = q @ k^T (+bias +mask), softmax rows ----
  {
    f32x4 sacc[4][4];
#pragma unroll
    for (int rt = 0; rt < 4; ++rt)
#pragma unroll
      for (int ct = 0; ct < 4; ++ct) sacc[rt][ct] = (f32x4){0.f, 0.f, 0.f, 0.f};

    bf16x8 a[4], bb[4];
#pragma unroll
    for (int rt = 0; rt < 4; ++rt) a[rt] = ldf(qh + (rt * 16 + l16) * QS + quad * 8);
#pragma unroll
    for (int ct = 0; ct < 4; ++ct) bb[ct] = ldf(kh + (ct * 16 + l16) * QS + quad * 8);
#pragma unroll
    for (int rt = 0; rt < 4; ++rt)
#pragma unroll
      for (int ct = 0; ct < 4; ++ct) sacc[rt][ct] = MFMA16(a[rt], bb[ct], sacc[rt][ct]);

    const float* rbh = rb + h * (WIN * WIN);
    const float* mw = mask + (size_t)(b & (NW - 1)) * (WIN * WIN);
#pragma unroll
    for (int rt = 0; rt < 4; ++rt) {
#pragma unroll
      for (int r = 0; r < 4; ++r) {
        int row = rt * 16 + quad * 4 + r;
        float vals[4];
#pragma unroll
        for (int ct = 0; ct < 4; ++ct) {
          int col = ct * 16 + l16;
          vals[ct] = sacc[rt][ct][r] + rbh[row * 64 + col] + mw[row * 64 + col];
        }
        float m = fmaxf(fmaxf(vals[0], vals[1]), fmaxf(vals[2], vals[3]));
#pragma unroll
        for (int o = 1; o < 16; o <<= 1) m = fmaxf(m, __shfl_xor(m, o, 64));
        float s = 0.f;
#pragma unroll
        for (int ct = 0; ct < 4; ++ct) { vals[ct] = __expf(vals[ct] - m); s += vals[ct]; }
#pragma unroll
        for (int o = 1; o < 16; o <<= 1) s += __shfl_xor(s, o, 64);
        float inv = 1.0f / s;
#pragma unroll
        for (int ct = 0; ct < 4; ++ct)
          ph[row * PS + ct * 16 + l16] = f2bf(vals[ct] * inv);   // overwrites dead q/k
      }
    }
  }

  // ---- Phase 4: O = P @ v  (64 x 32) ----
  {
    f32x4 oacc[2][4];
#pragma unroll
    for (int jt = 0; jt < 2; ++jt)
#pragma unroll
      for (int rt = 0; rt < 4; ++rt) oacc[jt][rt] = (f32x4){0.f, 0.f, 0.f, 0.f};

#pragma unroll
    for (int km = 0; km < 2; ++km) {
      int k0 = km * 32 + quad * 8;
      bf16x8 a[4], bb[2];
#pragma unroll
      for (int rt = 0; rt < 4; ++rt) a[rt] = ldf(ph + (rt * 16 + l16) * PS + k0);
#pragma unroll
      for (int jt = 0; jt < 2; ++jt) bb[jt] = ldf(vth + (jt * 16 + l16) * VS + k0);
#pragma unroll
      for (int jt = 0; jt < 2; ++jt)
#pragma unroll
        for (int rt = 0; rt < 4; ++rt) oacc[jt][rt] = MFMA16(a[rt], bb[jt], oacc[jt][rt]);
    }
    // write attn-out (bf16) into xs region: [64][XS], head h owns cols h*32..h*32+31
#pragma unroll
    for (int jt = 0; jt < 2; ++jt)
#pragma unroll
      for (int rt = 0; rt < 4; ++rt)
#pragma unroll
        for (int r = 0; r < 4; ++r) {
          int row = rt * 16 + quad * 4 + r;
          xs[row * XS + h * 32 + jt * 16 + l16] = f2bf(oacc[jt][rt][r]);
        }
  }
  __syncthreads();   // attn-out visible to all waves

  // ---- Phase 5: proj GEMM, wave computes cols [h*32, h*32+32), K=256 ----
  {
    f32x4 pacc[2][4];
#pragma unroll
    for (int ct = 0; ct < 2; ++ct)
#pragma unroll
      for (int rt = 0; rt < 4; ++rt) pacc[ct][rt] = (f32x4){0.f, 0.f, 0.f, 0.f};

#pragma unroll
    for (int kk = 0; kk < 8; ++kk) {
      int k0 = kk * 32 + quad * 8;
      bf16x8 a[4], bb[2];
#pragma unroll
      for (int rt = 0; rt < 4; ++rt) a[rt] = ldf(xs + (rt * 16 + l16) * XS + k0);
#pragma unroll
      for (int ct = 0; ct < 2; ++ct)
        bb[ct] = ldf(wproj_t + (h * 32 + ct * 16 + l16) * 256 + k0);
#pragma unroll
      for (int ct = 0; ct < 2; ++ct)
#pragma unroll
        for (int rt = 0; rt < 4; ++rt) pacc[ct][rt] = MFMA16(a[rt], bb[ct], pacc[ct][rt]);
    }
#pragma unroll
    for (int ct = 0; ct < 2; ++ct) {
      int col = h * 32 + ct * 16 + l16;
      float bias = b_proj[col];
#pragma unroll
      for (int rt = 0; rt < 4; ++rt)
#pragma unroll
        for (int r = 0; r < 4; ++r) {
          int row = rt * 16 + quad * 4 + r;
          out[(size_t)(b * WIN + row) * DIM + col] = pacc[ct][rt][r] + bias;
        }
    }
  }
}

extern "C" void kernel_launch(void* const* d_in, const int* in_sizes, int n_in,
                              void* d_out, int out_size, void* d_ws, size_t ws_size,
                              hipStream_t stream) {
  const float* x          = (const float*)d_in[0];
  const float* mask       = (const float*)d_in[1];
  const float* w_qkv      = (const float*)d_in[2];
  const float* b_qkv      = (const float*)d_in[3];
  const float* w_proj     = (const float*)d_in[4];
  const float* b_proj     = (const float*)d_in[5];
  const float* bias_table = (const float*)d_in[6];

  // workspace layout (bytes): wqkv_t 393216 | wproj_t 131072 | bqkv_s 3072 | rb 131072
  unsigned short* wqkv_t  = (unsigned short*)d_ws;
  unsigned short* wproj_t = wqkv_t + 768 * 256;
  float* bqkv_s           = (float*)(wproj_t + 256 * 256);
  float* rb               = bqkv_s + 768;

  prep_kernel<<<768, 256, 0, stream>>>(w_qkv, b_qkv, w_proj, bias_table,
                                       wqkv_t, wproj_t, bqkv_s, rb);

  (void)hipFuncSetAttribute((const void*)fused_attn,
                            hipFuncAttributeMaxDynamicSharedMemorySize,
                            LDS_ELEMS * 2);
  fused_attn<<<4096, 512, LDS_ELEMS * 2, stream>>>(
      x, mask, b_proj, wqkv_t, wproj_t, bqkv_s, rb, (float*)d_out);
}

// Round 2
// 785.133 us; speedup vs baseline: 1.0658x; 1.0658x over previous
//
#include <hip/hip_runtime.h>
#include <hip/hip_bf16.h>

#define DIM 256
#define WIN 64
#define HEADS 8
#define HD 32
#define NW 64

typedef __attribute__((ext_vector_type(8))) short bf16x8;
typedef __attribute__((ext_vector_type(4))) float f32x4;

// LDS layout (elements of unsigned short / bf16)
#define XS 264                  // x / attn-out row stride (256 + 8 pad)
#define QS 40                   // q,k row stride (80 B: 16B aligned, 2-way banks)
#define VS 72                   // v-transposed row stride (144 B)
#define PS 72                   // P row stride
#define HREG 7424               // per-head region: q(64*40) + k(64*40) + vt(32*72)
#define LDS_ELEMS (WIN * XS + HEADS * HREG)   // 16896 + 59392 = 76288 (152576 B)

__device__ __forceinline__ unsigned short f2bf(float f) {
  union { float f; unsigned u; } v; v.f = f;
  unsigned r = v.u + 0x7FFFu + ((v.u >> 16) & 1u);   // RNE
  return (unsigned short)(r >> 16);
}

__device__ __forceinline__ bf16x8 ldf(const unsigned short* p) {
  return *reinterpret_cast<const bf16x8*>(p);
}

#define MFMA16(a, b, c) __builtin_amdgcn_mfma_f32_16x16x32_bf16(a, b, c, 0, 0, 0)

// ---------------------------------------------------------------------------
// Prep: transpose+convert weights to bf16 (fold softmax scale into q cols),
// scale q bias, pre-gather relative-position bias rb[h][n][m].
// ---------------------------------------------------------------------------
__global__ void prep_kernel(const float* __restrict__ w_qkv,
                            const float* __restrict__ b_qkv,
                            const float* __restrict__ w_proj,
                            const float* __restrict__ bias_table,
                            unsigned short* __restrict__ wqkv_t,   // [768][256]
                            unsigned short* __restrict__ wproj_t,  // [256][256]
                            float* __restrict__ bqkv_s,            // [768]
                            float* __restrict__ rb) {              // [8][64][64]
  const float SCALE = 0.1767766952966369f;  // 32^-0.5
  int idx = blockIdx.x * blockDim.x + threadIdx.x;
  if (idx < 768 * 256) {
    int n = idx >> 8, k = idx & 255;
    float v = w_qkv[k * 768 + n];
    if (n < 256) v *= SCALE;               // q columns get the scale
    wqkv_t[idx] = f2bf(v);
  }
  if (idx < 256 * 256) {
    int n = idx >> 8, k = idx & 255;
    wproj_t[idx] = f2bf(w_proj[k * 256 + n]);
  }
  if (idx < 768) {
    float v = b_qkv[idx];
    if (idx < 256) v *= SCALE;
    bqkv_s[idx] = v;
  }
  if (idx < HEADS * WIN * WIN) {
    int h = idx >> 12;                     // / 4096
    int r = idx & 4095;
    int n = r >> 6, m = r & 63;
    rb[idx] = bias_table[(n - m + WIN - 1) * HEADS + h];
  }
}

// ---------------------------------------------------------------------------
// Fused window attention: one block per window, 16 waves, wave-PAIR per head.
//   sub = wave&1 splits work within a head pair so global weight loads are
//   NOT duplicated (qkv split by col-tiles, S/O by row halves, proj by cols).
// ---------------------------------------------------------------------------
__global__ __launch_bounds__(1024, 4) void fused_attn(
    const float* __restrict__ x,          // [4096][64][256]
    const float* __restrict__ mask,       // [64][64][64]
    const float* __restrict__ b_proj,     // [256]
    const unsigned short* __restrict__ wqkv_t,   // [768][256] bf16
    const unsigned short* __restrict__ wproj_t,  // [256][256] bf16
    const float* __restrict__ bqkv_s,     // [768]
    const float* __restrict__ rb,         // [8][64][64]
    float* __restrict__ out) {            // [4096][64][256]
  extern __shared__ unsigned short lds[];
  unsigned short* xs = lds;                                   // [64][XS], later attn-out
  const int tid = threadIdx.x;
  const int wave = tid >> 6;
  const int lane = tid & 63;
  const int l16 = lane & 15;
  const int quad = lane >> 4;
  const int b = blockIdx.x;
  const int h = wave >> 1;            // head index (wave pair)
  const int sub = wave & 1;           // half within the pair

  unsigned short* qh = lds + WIN * XS + h * HREG;             // [64][QS]
  unsigned short* kh = qh + 64 * QS;                          // [64][QS]
  unsigned short* vth = qh + 2 * 64 * QS;                     // [32][VS]
  unsigned short* ph = qh;                                    // [64][PS] overlays q,k

  // ---- Phase 1: load x window -> LDS bf16 (packed 8B stores) ----
  const float4* xg = reinterpret_cast<const float4*>(x + (size_t)b * (WIN * DIM));
#pragma unroll
  for (int i = 0; i < 4; ++i) {
    int e = tid + i * 1024;            // float4 index, 4096 total
    float4 f = xg[e];
    int n = e >> 6;
    int c = (e & 63) << 2;
    ushort4 s4;
    s4.x = f2bf(f.x); s4.y = f2bf(f.y); s4.z = f2bf(f.z); s4.w = f2bf(f.w);
    *reinterpret_cast<ushort4*>(xs + n * XS + c) = s4;
  }
  __syncthreads();

  // ---- Phase 2: qkv GEMM. Pair splits 6 col-tiles: this wave does
  //      ctp = sub*3 + c (c=0..2), all 64 rows, K=256. No dup weight loads. ----
  {
    f32x4 acc[3][4];
#pragma unroll
    for (int c = 0; c < 3; ++c)
#pragma unroll
      for (int rt = 0; rt < 4; ++rt) acc[c][rt] = (f32x4){0.f, 0.f, 0.f, 0.f};

#pragma unroll
    for (int kk = 0; kk < 8; ++kk) {
      int k0 = kk * 32 + quad * 8;
      bf16x8 a[4], bb[3];
#pragma unroll
      for (int rt = 0; rt < 4; ++rt) a[rt] = ldf(xs + (rt * 16 + l16) * XS + k0);
#pragma unroll
      for (int c = 0; c < 3; ++c) {
        int ctp = sub * 3 + c;
        int cbase = h * 32 + (ctp >> 1) * 256 + (ctp & 1) * 16;   // q|k|v column
        bb[c] = ldf(wqkv_t + (cbase + l16) * 256 + k0);
      }
#pragma unroll
      for (int c = 0; c < 3; ++c)
#pragma unroll
        for (int rt = 0; rt < 4; ++rt) acc[c][rt] = MFMA16(a[rt], bb[c], acc[c][rt]);
    }

    // store q,k row-major [64][QS]; v transposed [32][VS]
#pragma unroll
    for (int c = 0; c < 3; ++c) {
      int ctp = sub * 3 + c;
      int cbase = h * 32 + (ctp >> 1) * 256 + (ctp & 1) * 16;
      float bias = bqkv_s[cbase + l16];
#pragma unroll
      for (int rt = 0; rt < 4; ++rt)
#pragma unroll
        for (int r = 0; r < 4; ++r) {
          int row = rt * 16 + quad * 4 + r;
          unsigned short bv = f2bf(acc[c][rt][r] + bias);
          if (ctp < 2)      qh[row * QS + ctp * 16 + l16] = bv;
          else if (ctp < 4) kh[row * QS + (ctp - 2) * 16 + l16] = bv;
          else              vth[((ctp - 4) * 16 + l16) * VS + row] = bv;
        }
    }
  }
  __syncthreads();   // q,k,vt complete (pair wrote disjoint parts); xs -> attn-out

  // ---- Phase 3: S = q @ k^T (+bias +mask), softmax. Pair splits rows:
  //      this wave owns rows [sub*32, sub*32+32). ----
  {
    f32x4 sacc[2][4];
#pragma unroll
    for (int rt = 0; rt < 2; ++rt)
#pragma unroll
      for (int ct = 0; ct < 4; ++ct) sacc[rt][ct] = (f32x4){0.f, 0.f, 0.f, 0.f};

    bf16x8 a[2], bb[4];
#pragma unroll
    for (int rt = 0; rt < 2; ++rt)
      a[rt] = ldf(qh + (sub * 32 + rt * 16 + l16) * QS + quad * 8);
#pragma unroll
    for (int ct = 0; ct < 4; ++ct) bb[ct] = ldf(kh + (ct * 16 + l16) * QS + quad * 8);
#pragma unroll
    for (int rt = 0; rt < 2; ++rt)
#pragma unroll
      for (int ct = 0; ct < 4; ++ct) sacc[rt][ct] = MFMA16(a[rt], bb[ct], sacc[rt][ct]);

    const float* rbh = rb + h * (WIN * WIN);
    const float* mw = mask + (size_t)(b & (NW - 1)) * (WIN * WIN);
#pragma unroll
    for (int rt = 0; rt < 2; ++rt) {
#pragma unroll
      for (int r = 0; r < 4; ++r) {
        int row = sub * 32 + rt * 16 + quad * 4 + r;
        float vals[4];
#pragma unroll
        for (int ct = 0; ct < 4; ++ct) {
          int col = ct * 16 + l16;
          vals[ct] = sacc[rt][ct][r] + rbh[row * 64 + col] + mw[row * 64 + col];
        }
        float m = fmaxf(fmaxf(vals[0], vals[1]), fmaxf(vals[2], vals[3]));
#pragma unroll
        for (int o = 1; o < 16; o <<= 1) m = fmaxf(m, __shfl_xor(m, o, 64));
        float s = 0.f;
#pragma unroll
        for (int ct = 0; ct < 4; ++ct) { vals[ct] = __expf(vals[ct] - m); s += vals[ct]; }
#pragma unroll
        for (int o = 1; o < 16; o <<= 1) s += __shfl_xor(s, o, 64);
        float inv = 1.0f / s;
#pragma unroll
        for (int ct = 0; ct < 4; ++ct)
          ph[row * PS + ct * 16 + l16] = f2bf(vals[ct] * inv);   // overwrites dead q/k
      }
    }
  }
  // P rows [sub*32, sub*32+32) are wave-private between phase 3 and 4: no sync.

  // ---- Phase 4: O = P @ v (this wave: its 32 rows x 32 dims) ----
  {
    f32x4 oacc[2][2];
#pragma unroll
    for (int jt = 0; jt < 2; ++jt)
#pragma unroll
      for (int rt = 0; rt < 2; ++rt) oacc[jt][rt] = (f32x4){0.f, 0.f, 0.f, 0.f};

#pragma unroll
    for (int km = 0; km < 2; ++km) {
      int k0 = km * 32 + quad * 8;
      bf16x8 a[2], bb[2];
#pragma unroll
      for (int rt = 0; rt < 2; ++rt)
        a[rt] = ldf(ph + (sub * 32 + rt * 16 + l16) * PS + k0);
#pragma unroll
      for (int jt = 0; jt < 2; ++jt) bb[jt] = ldf(vth + (jt * 16 + l16) * VS + k0);
#pragma unroll
      for (int jt = 0; jt < 2; ++jt)
#pragma unroll
        for (int rt = 0; rt < 2; ++rt) oacc[jt][rt] = MFMA16(a[rt], bb[jt], oacc[jt][rt]);
    }
    // write attn-out (bf16) into xs region: head h owns cols h*32..h*32+31
#pragma unroll
    for (int jt = 0; jt < 2; ++jt)
#pragma unroll
      for (int rt = 0; rt < 2; ++rt)
#pragma unroll
        for (int r = 0; r < 4; ++r) {
          int row = sub * 32 + rt * 16 + quad * 4 + r;
          xs[row * XS + h * 32 + jt * 16 + l16] = f2bf(oacc[jt][rt][r]);
        }
  }
  __syncthreads();   // attn-out visible to all waves

  // ---- Phase 5: proj GEMM. This wave: cols [h*32+sub*16, +16), all 64 rows. ----
  {
    f32x4 pacc[4];
#pragma unroll
    for (int rt = 0; rt < 4; ++rt) pacc[rt] = (f32x4){0.f, 0.f, 0.f, 0.f};
    const int col = h * 32 + sub * 16 + l16;

#pragma unroll
    for (int kk = 0; kk < 8; ++kk) {
      int k0 = kk * 32 + quad * 8;
      bf16x8 a[4], bb;
#pragma unroll
      for (int rt = 0; rt < 4; ++rt) a[rt] = ldf(xs + (rt * 16 + l16) * XS + k0);
      bb = ldf(wproj_t + col * 256 + k0);
#pragma unroll
      for (int rt = 0; rt < 4; ++rt) pacc[rt] = MFMA16(a[rt], bb, pacc[rt]);
    }
    float bias = b_proj[col];
#pragma unroll
    for (int rt = 0; rt < 4; ++rt)
#pragma unroll
      for (int r = 0; r < 4; ++r) {
        int row = rt * 16 + quad * 4 + r;
        out[(size_t)(b * WIN + row) * DIM + col] = pacc[rt][r] + bias;
      }
  }
}

extern "C" void kernel_launch(void* const* d_in, const int* in_sizes, int n_in,
                              void* d_out, int out_size, void* d_ws, size_t ws_size,
                              hipStream_t stream) {
  const float* x          = (const float*)d_in[0];
  const float* mask       = (const float*)d_in[1];
  const float* w_qkv      = (const float*)d_in[2];
  const float* b_qkv      = (const float*)d_in[3];
  const float* w_proj     = (const float*)d_in[4];
  const float* b_proj     = (const float*)d_in[5];
  const float* bias_table = (const float*)d_in[6];

  // workspace layout (bytes): wqkv_t 393216 | wproj_t 131072 | bqkv_s 3072 | rb 131072
  unsigned short* wqkv_t  = (unsigned short*)d_ws;
  unsigned short* wproj_t = wqkv_t + 768 * 256;
  float* bqkv_s           = (float*)(wproj_t + 256 * 256);
  float* rb               = bqkv_s + 768;

  prep_kernel<<<768, 256, 0, stream>>>(w_qkv, b_qkv, w_proj, bias_table,
                                       wqkv_t, wproj_t, bqkv_s, rb);

  (void)hipFuncSetAttribute((const void*)fused_attn,
                            hipFuncAttributeMaxDynamicSharedMemorySize,
                            LDS_ELEMS * 2);
  fused_attn<<<4096, 1024, LDS_ELEMS * 2, stream>>>(
      x, mask, b_proj, wqkv_t, wproj_t, bqkv_s, rb, (float*)d_out);
}